// Round 1
// baseline (195.144 us; speedup 1.0000x reference)
//
#include <hip/hip_runtime.h>
#include <math.h>

// Problem constants (from reference)
#define NB      2048        // batch
#define DIM     256         // input dim
#define SC6     192         // S*6 = 32 splines * 6 params
#define CV      128         // canvas size
#define NT      50          // samples along curve
// W_STAMP = -0.07, BG = 0.3, SCALE = 1e-4

// log_prob per batch = 192*( -ln(1e-4) - 0.5*ln(2*pi) )  (raw == mu exactly)
// entropy  per batch = 192*( 0.5 + 0.5*ln(2*pi) + ln(1e-4) )
#define LPV  (1591.9491530441301f)
#define ENV  (-1495.9491530441301f)

// Output layout (flat, return order): sketch | log_prob | entropy | sample
#define SKETCH_N   ((size_t)NB * CV * CV)     // 33,554,432
#define LP_OFF     (SKETCH_N)
#define ENT_OFF    (LP_OFF + NB)
#define SAMPLE_OFF (ENT_OFF + NB)

// ---------------------------------------------------------------------------
// Kernel A: mu = x @ W + b  (f64 accumulate), sigmoid (f64), emit:
//   - sample (f32) to d_out
//   - params = sigmoid*128 (f64) to workspace (decision-critical precision)
//   - log_prob / entropy constants
// 8 batches per block, 192 threads (one output column each).
// ---------------------------------------------------------------------------
__global__ __launch_bounds__(192) void gemm_sig_kernel(
    const float* __restrict__ x, const float* __restrict__ W,
    const float* __restrict__ bias, float* __restrict__ out,
    double* __restrict__ params)
{
    __shared__ float xt[DIM * 8];            // xt[d*8 + i], transposed x tile
    const int b0  = blockIdx.x * 8;
    const int tid = threadIdx.x;

    for (int idx = tid; idx < DIM * 8; idx += 192) {
        int i = idx >> 8;        // batch within tile
        int d = idx & 255;       // input dim
        xt[d * 8 + i] = x[(size_t)(b0 + i) * DIM + d];
    }
    __syncthreads();

    const int j = tid;           // output column 0..191
    double acc[8] = {0, 0, 0, 0, 0, 0, 0, 0};

    #pragma unroll 4
    for (int d = 0; d < DIM; ++d) {
        double wd = (double)W[d * SC6 + j];
        const float4* xp = (const float4*)(&xt[d * 8]);
        float4 xa = xp[0];
        float4 xb = xp[1];
        acc[0] = fma((double)xa.x, wd, acc[0]);
        acc[1] = fma((double)xa.y, wd, acc[1]);
        acc[2] = fma((double)xa.z, wd, acc[2]);
        acc[3] = fma((double)xa.w, wd, acc[3]);
        acc[4] = fma((double)xb.x, wd, acc[4]);
        acc[5] = fma((double)xb.y, wd, acc[5]);
        acc[6] = fma((double)xb.z, wd, acc[6]);
        acc[7] = fma((double)xb.w, wd, acc[7]);
    }

    const double bj = (double)bias[j];
    float* out_sample = out + SAMPLE_OFF;

    #pragma unroll
    for (int i = 0; i < 8; ++i) {
        double mu = acc[i] + bj;
        double s  = 1.0 / (1.0 + exp(-mu));
        out_sample[(size_t)(b0 + i) * SC6 + j] = (float)s;
        params[(size_t)(b0 + i) * SC6 + j]     = s * 128.0;  // CANVAS scale
    }

    if (j < 8) {
        out[LP_OFF  + b0 + j] = LPV;
        out[ENT_OFF + b0 + j] = ENV;
    }
}

// ---------------------------------------------------------------------------
// Kernel B: rasterize 32 quadratic Beziers per batch into a 128x128 canvas.
// LDS canvas = packed u16 counts (2 px / u32 word, 32 KB). Max stamps per
// batch = 32*50*9 = 14400 < 65536 -> no cross-half carry possible.
// canvas value = clip(0.3 - 0.07*count, 0, 1), computed in f64, stored f32.
// ---------------------------------------------------------------------------
__global__ __launch_bounds__(256) void paint_kernel(
    const double* __restrict__ params, float* __restrict__ out)
{
    __shared__ unsigned int cnt[CV * CV / 2];   // 8192 words = 32 KB
    __shared__ double sp[SC6];

    const int b   = blockIdx.x;
    const int tid = threadIdx.x;

    for (int w = tid; w < CV * CV / 2; w += 256) cnt[w] = 0u;
    if (tid < SC6) sp[tid] = params[(size_t)b * SC6 + tid];
    __syncthreads();

    // 32 splines * 50 t-samples = 1600 points; 9 stamps each.
    for (int i = tid; i < 32 * NT; i += 256) {
        int s = i / NT;
        int k = i - s * NT;
        // np.linspace(0,1,50): t_k = k * fl64(1/49), endpoint forced to 1.0
        double t = (k == NT - 1) ? 1.0 : (double)k * (1.0 / 49.0);
        double u = 1.0 - t;
        double a  = u * u;            // (1-t)**2
        double bq = (2.0 * u) * t;    // 2*(1-t)*t  (reference assoc order)
        double c  = t * t;            // t**2
        const double* P = &sp[s * 6];
        double px = a * P[0] + bq * P[2] + c * P[4];
        double py = a * P[1] + bq * P[3] + c * P[5];
        int cx = (int)rint(px);       // round-half-even, matches np.round
        int cy = (int)rint(py);
        #pragma unroll
        for (int dx = -1; dx <= 1; ++dx) {
            #pragma unroll
            for (int dy = -1; dy <= 1; ++dy) {
                int xi = min(max(cx + dx, 0), CV - 1);
                int yi = min(max(cy + dy, 0), CV - 1);
                int p  = xi * CV + yi;
                atomicAdd(&cnt[p >> 1], 1u << ((p & 1) << 4));
            }
        }
    }
    __syncthreads();

    // Epilogue: clip(0.3 - 0.07*count, 0, 1), coalesced float4 stores.
    float4* ob = (float4*)(out + (size_t)b * CV * CV);
    const uint2* c2 = (const uint2*)cnt;
    for (int w = tid; w < CV * CV / 8; w += 256) {
        uint2 v = c2[w];
        unsigned int c0 = v.x & 0xFFFFu;
        unsigned int c1 = v.x >> 16;
        unsigned int c2v = v.y & 0xFFFFu;
        unsigned int c3 = v.y >> 16;
        double r0 = 0.3 - 0.07 * (double)c0;
        double r1 = 0.3 - 0.07 * (double)c1;
        double r2 = 0.3 - 0.07 * (double)c2v;
        double r3 = 0.3 - 0.07 * (double)c3;
        float4 r;
        r.x = (float)(r0 < 0.0 ? 0.0 : (r0 > 1.0 ? 1.0 : r0));
        r.y = (float)(r1 < 0.0 ? 0.0 : (r1 > 1.0 ? 1.0 : r1));
        r.z = (float)(r2 < 0.0 ? 0.0 : (r2 > 1.0 ? 1.0 : r2));
        r.w = (float)(r3 < 0.0 ? 0.0 : (r3 > 1.0 ? 1.0 : r3));
        ob[w] = r;
    }
}

extern "C" void kernel_launch(void* const* d_in, const int* in_sizes, int n_in,
                              void* d_out, int out_size, void* d_ws, size_t ws_size,
                              hipStream_t stream) {
    const float* x    = (const float*)d_in[0];   // [2048, 256]
    const float* W    = (const float*)d_in[1];   // [256, 192]
    const float* bias = (const float*)d_in[2];   // [192]
    float* out = (float*)d_out;
    double* params = (double*)d_ws;              // [2048, 192] f64 = 3.15 MB

    gemm_sig_kernel<<<NB / 8, 192, 0, stream>>>(x, W, bias, out, params);
    paint_kernel<<<NB, 256, 0, stream>>>(params, out);
}

// Round 2
// 168.203 us; speedup vs baseline: 1.1602x; 1.1602x over previous
//
#include <hip/hip_runtime.h>
#include <math.h>

// Problem constants (from reference)
#define NB      2048        // batch
#define DIM     256         // input dim
#define SC6     192         // S*6 = 32 splines * 6 params
#define CV      128         // canvas size
#define NT      50          // samples along curve
// W_STAMP = -0.07, BG = 0.3, SCALE = 1e-4

// log_prob per batch = 192*( -ln(1e-4) - 0.5*ln(2*pi) )  (raw == mu exactly)
// entropy  per batch = 192*( 0.5 + 0.5*ln(2*pi) + ln(1e-4) )
#define LPV  (1591.9491530441301f)
#define ENV  (-1495.9491530441301f)

// Output layout (flat, return order): sketch | log_prob | entropy | sample
#define SKETCH_N   ((size_t)NB * CV * CV)     // 33,554,432
#define LP_OFF     (SKETCH_N)
#define ENT_OFF    (LP_OFF + NB)
#define SAMPLE_OFF (ENT_OFF + NB)

// ---------------------------------------------------------------------------
// Fused kernel: one block per batch.
// Phase 1 (192 of 256 threads): mu_j = sum_d x[b,d]*W[d,j] in f64 (sequential
//   d=0..255 -> bit-identical to the R1-passing version), sigmoid in f64,
//   sample -> global, params = s*128 -> LDS.
// Phase 2: rasterize 32 quadratic Beziers into a packed-u16 LDS canvas
//   (2 px / u32 word; max 14400 stamps/batch < 65536 so no carry), with
//   a per-row bank swizzle and 6 atomics/point (y-triple packed into 2 words).
// Epilogue: clip(0.3 - 0.07*count, 0, 1), coalesced float4 stores.
// ---------------------------------------------------------------------------
__global__ __launch_bounds__(256) void fused_kernel(
    const float* __restrict__ x, const float* __restrict__ W,
    const float* __restrict__ bias, float* __restrict__ out)
{
    __shared__ unsigned int cnt[CV * CV / 2];   // 8192 words = 32 KB
    __shared__ double sp[SC6];                  // params*128 for this batch
    __shared__ float  xs[DIM];                  // x[b, :]

    const int b   = blockIdx.x;
    const int tid = threadIdx.x;

    // zero canvas with wide stores (2048 uint4 words / 256 thr = 8 each)
    {
        uint4* c4 = (uint4*)cnt;
        uint4 z = make_uint4(0u, 0u, 0u, 0u);
        #pragma unroll
        for (int w = 0; w < 8; ++w) c4[tid + 256 * w] = z;
    }
    xs[tid] = x[(size_t)b * DIM + tid];
    if (tid == 192) out[LP_OFF  + b] = LPV;
    if (tid == 193) out[ENT_OFF + b] = ENV;
    __syncthreads();

    // ---- Phase 1: gemm + sigmoid (f64, exact order preserved) ----
    if (tid < SC6) {
        const int j = tid;
        double acc = 0.0;
        #pragma unroll 8
        for (int d = 0; d < DIM; ++d) {
            acc = fma((double)xs[d], (double)W[d * SC6 + j], acc);
        }
        double mu = acc + (double)bias[j];
        double s  = 1.0 / (1.0 + exp(-mu));
        out[SAMPLE_OFF + (size_t)b * SC6 + j] = (float)s;
        sp[j] = s * 128.0;                       // CANVAS scale
    }
    __syncthreads();

    // ---- Phase 2: paint. lane map s=i%32 scatters lanes across splines ----
    for (int i = tid; i < 32 * NT; i += 256) {
        int s = i & 31;
        int k = i >> 5;                          // 0..49
        // np.linspace(0,1,50): t_k = k * fl64(1/49), endpoint forced to 1.0
        double t = (k == NT - 1) ? 1.0 : (double)k * (1.0 / 49.0);
        double u = 1.0 - t;
        double a  = u * u;                       // (1-t)**2
        double bq = (2.0 * u) * t;               // 2*(1-t)*t (ref assoc order)
        double c  = t * t;                       // t**2
        const double* P = &sp[s * 6];
        double px = a * P[0] + bq * P[2] + c * P[4];
        double py = a * P[1] + bq * P[3] + c * P[5];
        int cx = (int)rint(px);                  // round-half-even == np.round
        int cy = (int)rint(py);

        // clipped y-triple -> packed increments for 2 adjacent u16-pair words
        int y0 = min(max(cy - 1, 0), CV - 1);
        int y1 = min(max(cy,     0), CV - 1);
        int y2 = min(max(cy + 1, 0), CV - 1);
        int cb = y0 >> 1;                        // base word-column
        unsigned incA = 1u << ((y0 & 1) << 4);
        unsigned incB = 0u;
        unsigned i1 = 1u << ((y1 & 1) << 4);
        unsigned i2 = 1u << ((y2 & 1) << 4);
        if ((y1 >> 1) == cb) incA += i1; else incB += i1;
        if ((y2 >> 1) == cb) incA += i2; else incB += i2;

        int x0 = min(max(cx - 1, 0), CV - 1);
        int x1 = min(max(cx,     0), CV - 1);
        int x2 = min(max(cx + 1, 0), CV - 1);
        int rows[3] = {x0, x1, x2};
        #pragma unroll
        for (int r = 0; r < 3; ++r) {
            int xi = rows[r];
            int base = xi << 6;
            int sw = 3 * xi;
            atomicAdd(&cnt[base + ((cb + sw) & 63)], incA);
            if (incB) atomicAdd(&cnt[base + ((cb + 1 + sw) & 63)], incB);
        }
    }
    __syncthreads();

    // ---- Epilogue: clip(0.3 - 0.07*count, 0, 1), float4 stores ----
    float4* ob = (float4*)(out + (size_t)b * CV * CV);
    for (int w = tid; w < CV * CV / 4; w += 256) {
        int pb = w << 2;                         // pixel base (multiple of 4)
        int xi = pb >> 7;                        // row
        int c0 = (pb >> 1) & 63;                 // even word-column
        int base = xi << 6;
        int sw = 3 * xi;
        unsigned v0 = cnt[base + ((c0 + sw) & 63)];
        unsigned v1 = cnt[base + ((c0 + 1 + sw) & 63)];
        unsigned k0 = v0 & 0xFFFFu, k1 = v0 >> 16;
        unsigned k2 = v1 & 0xFFFFu, k3 = v1 >> 16;
        double r0 = 0.3 - 0.07 * (double)k0;
        double r1 = 0.3 - 0.07 * (double)k1;
        double r2 = 0.3 - 0.07 * (double)k2;
        double r3 = 0.3 - 0.07 * (double)k3;
        float4 r;
        r.x = (float)(r0 < 0.0 ? 0.0 : (r0 > 1.0 ? 1.0 : r0));
        r.y = (float)(r1 < 0.0 ? 0.0 : (r1 > 1.0 ? 1.0 : r1));
        r.z = (float)(r2 < 0.0 ? 0.0 : (r2 > 1.0 ? 1.0 : r2));
        r.w = (float)(r3 < 0.0 ? 0.0 : (r3 > 1.0 ? 1.0 : r3));
        ob[w] = r;
    }
}

extern "C" void kernel_launch(void* const* d_in, const int* in_sizes, int n_in,
                              void* d_out, int out_size, void* d_ws, size_t ws_size,
                              hipStream_t stream) {
    const float* x    = (const float*)d_in[0];   // [2048, 256]
    const float* W    = (const float*)d_in[1];   // [256, 192]
    const float* bias = (const float*)d_in[2];   // [192]
    float* out = (float*)d_out;

    fused_kernel<<<NB, 256, 0, stream>>>(x, W, bias, out);
}